// Round 8
// baseline (198.902 us; speedup 1.0000x reference)
//
#include <hip/hip_runtime.h>
#include <stdint.h>

// Problem constants
#define B_      4
#define C_      3
#define H_      1024
#define W_      1024
#define OH_     31          // (1024-64)/32 + 1
#define NHS_    64          // 16-row half-strips per image
#define NP_     3844        // B * OH * OH
#define NPOSPB_ 961         // OH*OH
#define EPS_    1e-5f

#define NBLK_    256        // 256 blocks x 768 threads; 1 block/CU, co-resident
#define NTHR_    768
#define NSHARD_  8
#define SHARD_TGT_ 32       // 256 / 8
#define LINE_    32         // ints per 128B line
#define NSHADOW_ 8          // BN-stats shadow accumulators (cuts RMW contention 8x)

// ---------------- ws layout (float offsets) ----------------
#define TILE_PLANE 24576    // 12 bc * 64 hs * 32 tx
#define OFF_TILE  0         // 4 planes * 24576 = 98304
#define OFF_STATS 98304     // 8 shadows * 128 = 1024
#define OFF_A     99328     // 3 * 3844
#define OFF_BV    110860    // 3 * 3844  (end 122392 floats ~= 490 KB)

typedef float f4 __attribute__((ext_vector_type(4)));

// ---------------- parity-versioned barrier state (device globals, zero-init) ----------------
// 4 barriers x (8 shard lines + root), two parity sets. The unique block that
// completes the done-root resets the OTHER parity set and flips g_parity.
__device__ int g_b0s[2][NSHARD_ * LINE_]; __device__ int g_b0r[2][LINE_];
__device__ int g_b1s[2][NSHARD_ * LINE_]; __device__ int g_b1r[2][LINE_];
__device__ int g_b2s[2][NSHARD_ * LINE_]; __device__ int g_b2r[2][LINE_];
__device__ int g_b3s[2][NSHARD_ * LINE_]; __device__ int g_b3r[2][LINE_];
__device__ int g_parity;

// Round-6/7 lesson (proven): poll with RELAXED agent loads (read-through, no
// cache maintenance); ONE acquire load after the predicate passes does the
// single L1/L2 invalidate + ordering. Acquire-per-poll = L2-invalidate storm.
static __device__ __forceinline__ int  rload(int* p) { return __hip_atomic_load(p, __ATOMIC_RELAXED, __HIP_MEMORY_SCOPE_AGENT); }
static __device__ __forceinline__ int  aacq(int* p)  { return __hip_atomic_load(p, __ATOMIC_ACQUIRE, __HIP_MEMORY_SCOPE_AGENT); }
static __device__ __forceinline__ int  aadd(int* p, int v) { return __hip_atomic_fetch_add(p, v, __ATOMIC_ACQ_REL, __HIP_MEMORY_SCOPE_AGENT); }
static __device__ __forceinline__ void astoref(float* p, float v) { __hip_atomic_store(p, v, __ATOMIC_RELAXED, __HIP_MEMORY_SCOPE_AGENT); }
static __device__ __forceinline__ void astorei(int* p, int v)     { __hip_atomic_store(p, v, __ATOMIC_RELAXED, __HIP_MEMORY_SCOPE_AGENT); }
static __device__ __forceinline__ float aloadf(float* p) { return __hip_atomic_load(p, __ATOMIC_RELAXED, __HIP_MEMORY_SCOPE_AGENT); }

#define ARRIVE(shard, root) do { \
    if (t == 0) { \
        int _o = aadd(&(shard)[(fb & (NSHARD_ - 1)) * LINE_], 1); \
        if (_o == SHARD_TGT_ - 1) aadd(&(root)[0], 1); \
    } \
} while (0)
#define SPINROOT(root, slp) do { \
    if (t == 0) { \
        while (rload(&(root)[0]) < NSHARD_) __builtin_amdgcn_s_sleep(slp); \
        (void)aacq(&(root)[0]); \
    } \
    __syncthreads(); \
} while (0)

// ============================================================================
// Single fused kernel, 256 blocks x 768 threads, plain launch.
//  phase1: 3 half-strip units/block; g loaded ONCE, kept in 16 f4 REGISTERS
//          (phase-5 rows of (fb,sub,st) == phase-1 rows: row0 = 16*(3fb+sub));
//          g/s both nontemporal (each read exactly once); tile partials
//          agent-stored (no fences anywhere).
//  mid: ALL 256 blocks, 16 positions each, thread=(pos,ch) for t<512.
//          Tile->S sums: 8 loads/thread (t<192). Weights in LDS (w2 padded x33
//          -> conflict-free). BN stats: block partial -> 8 shadow accumulators
//          (<=32 RMW/address) -> read 8 shadows after sharded 256-wide barrier.
//  phase5: A/b gather (L2/L3) + out = A*g_regs + b, 48 rows/block, NT store.
//  Barriers: 4 x sharded (8x32 + root). Co-residency: 12 waves, ~12 KB LDS,
//          VGPR<=170 guaranteed by __launch_bounds__(768) -> 1 block/CU.
// ============================================================================
__global__ __launch_bounds__(NTHR_) void fused(
        const float* __restrict__ g,
        const float* __restrict__ s,
        const float* __restrict__ w1f,
        const float* __restrict__ g1f,
        const float* __restrict__ b1f,
        const float* __restrict__ w2f,
        const float* __restrict__ g2f,
        const float* __restrict__ b2f,
        const float* __restrict__ w3f,
        float* __restrict__ ws,
        float* __restrict__ out) {
    __shared__ float w1L[192];
    __shared__ float w2L[32 * 33];     // padded: bank (ch+i)&31 -> conflict-free
    __shared__ float w3L[3 * 33];
    __shared__ float Sarr[16][12];     // [pos][c*4+plane]
    __shared__ float hbuf[16][8];      // h[0..5]
    __shared__ float mxb[16][4], myb[16][4];
    __shared__ float sbuf[16][33];     // stats staging (y1, then y2)
    __shared__ float zbuf[16][33];     // z, then z2
    __shared__ float scs[32], shs[32];
    __shared__ int sP;
    int t  = threadIdx.x;
    int fb = blockIdx.x;
    if (t == 0) sP = rload(&g_parity);

    // weights -> LDS (first use is after bar0's syncthreads)
    if (t < 192) w1L[t] = w1f[t];
    for (int i = t; i < 1024; i += NTHR_) w2L[(i >> 5) * 33 + (i & 31)] = w2f[i];
    if (t < 96) w3L[(t >> 5) * 33 + (t & 31)] = w3f[t];

    // ---------------- phase 1: tile partial sums; g kept in registers ----------------
    int sub = t >> 8;                 // 0..2 (wave-aligned)
    int st  = t & 255;
    f4 gvals[16];
    {
        int unit = fb * 3 + sub;      // 0..767
        int ibc = unit >> 6, hs = unit & 63;
        const f4* gp = (const f4*)(g + ((size_t)ibc * H_ + (size_t)hs * 16) * W_);
        const f4* sp = (const f4*)(s + ((size_t)ibc * H_ + (size_t)hs * 16) * W_);
        float sg = 0.f, ss = 0.f, sgs = 0.f, sgg = 0.f;
#pragma unroll
        for (int r = 0; r < 16; r++) {      // FULL unroll: gvals[r] must be static
            f4 gv = __builtin_nontemporal_load(gp + r * (W_ / 4) + st);  // g read exactly once
            f4 sv = __builtin_nontemporal_load(sp + r * (W_ / 4) + st);  // s read exactly once
            gvals[r] = gv;
            sg  += (gv.x + gv.y) + (gv.z + gv.w);
            ss  += (sv.x + sv.y) + (sv.z + sv.w);
            sgs += gv.x * sv.x + gv.y * sv.y + gv.z * sv.z + gv.w * sv.w;
            sgg += gv.x * gv.x + gv.y * gv.y + gv.z * gv.z + gv.w * gv.w;
        }
#pragma unroll
        for (int off = 4; off; off >>= 1) {
            sg  += __shfl_down(sg,  off, 8);
            ss  += __shfl_down(ss,  off, 8);
            sgs += __shfl_down(sgs, off, 8);
            sgg += __shfl_down(sgg, off, 8);
        }
        if ((st & 7) == 0) {
            int tx = st >> 3;
            int base = (ibc * NHS_ + hs) * 32 + tx;
            astoref(&ws[OFF_TILE + 0 * TILE_PLANE + base], sg);
            astoref(&ws[OFF_TILE + 1 * TILE_PLANE + base], ss);
            astoref(&ws[OFF_TILE + 2 * TILE_PLANE + base], sgs);
            astoref(&ws[OFF_TILE + 3 * TILE_PLANE + base], sgg);
        }
        if (fb == 0) for (int i = t; i < NSHADOW_ * 128; i += NTHR_) astoref(&ws[OFF_STATS + i], 0.f);
    }
    __syncthreads();                  // drains vmcnt -> agent stores visible; sP broadcast
    int P = sP;
    ARRIVE(g_b0s[P], g_b0r[P]);

    // ================= mid: all 256 blocks, 16 positions each =================
    SPINROOT(g_b0r[P], 2);            // all tile partials visible (one invalidate)

    int p0 = fb * 16;
    // phase A1: window S sums, 8 scattered loads per thread (t<192)
    if (t < 192) {
        int ipos = t / 12, idx = t % 12;
        int c = idx >> 2, plane = idx & 3;
        int p = p0 + ipos; if (p >= NP_) p = 0;    // clamp (excluded downstream)
        int b = p / NPOSPB_, r = p % NPOSPB_;
        int oy = r / OH_, ox = r % OH_;
        const float* tp = ws + OFF_TILE + plane * TILE_PLANE + ((b * 3 + c) * NHS_ + oy * 2) * 32 + ox;
        Sarr[ipos][idx] = ((tp[0]  + tp[1])  + (tp[32] + tp[33]))
                        + ((tp[64] + tp[65]) + (tp[96] + tp[97]));
    }
    __syncthreads();
    // phase A2: h, mx, my
    if (t < 48) {
        int pos = t / 3, c = t % 3;
        const float inv = 1.f / 4096.f;
        float mx = Sarr[pos][c * 4 + 0] * inv, my = Sarr[pos][c * 4 + 1] * inv;
        hbuf[pos][c]     = Sarr[pos][c * 4 + 2] * inv - mx * my;
        hbuf[pos][3 + c] = Sarr[pos][c * 4 + 3] * inv - mx * mx;
        mxb[pos][c] = mx; myb[pos][c] = my;
    }
    __syncthreads();
    // conv1: thread (pos,ch), y1 in register across barriers
    int pos = t >> 5, ch = t & 31;
    bool act = t < 512;
    bool valid = act && (p0 + pos) < NP_;
    float y1 = 0.f;
    if (act) {
#pragma unroll
        for (int i = 0; i < 6; i++) y1 += w1L[ch * 6 + i] * hbuf[pos][i];  // broadcast reads
        sbuf[pos][ch] = valid ? y1 : 0.f;
    }
    __syncthreads();
    if (t < 32) {                     // block partial -> shadow accumulator
        float sv = 0.f, sq = 0.f;
#pragma unroll
        for (int i = 0; i < 16; i++) { float v = sbuf[i][t]; sv += v; sq += v * v; }
        float* sh0 = ws + OFF_STATS + (fb & (NSHADOW_ - 1)) * 128;
        atomicAdd(&sh0[t], sv); atomicAdd(&sh0[32 + t], sq);
    }
    __syncthreads();                  // drain atomics before arrival
    ARRIVE(g_b1s[P], g_b1r[P]);
    SPINROOT(g_b1r[P], 2);
    if (t < 32) {
        float sm = 0.f, sq = 0.f;
#pragma unroll
        for (int k = 0; k < NSHADOW_; k++) {
            sm += aloadf(&ws[OFF_STATS + k * 128 + t]);
            sq += aloadf(&ws[OFF_STATS + k * 128 + 32 + t]);
        }
        float m = sm * (1.f / NP_);
        float v = sq * (1.f / NP_) - m * m;
        float sc = g1f[t] * rsqrtf(v + EPS_);
        scs[t] = sc; shs[t] = b1f[t] - m * sc;
    }
    __syncthreads();
    // phase B: BN1+ReLU -> z(LDS) -> conv2
    if (act) zbuf[pos][ch] = fmaxf(y1 * scs[ch] + shs[ch], 0.f);
    __syncthreads();
    float y2 = 0.f;
    if (act) {
#pragma unroll
        for (int i = 0; i < 32; i++) y2 += w2L[ch * 33 + i] * zbuf[pos][i];  // conflict-free + broadcast
        sbuf[pos][ch] = valid ? y2 : 0.f;
    }
    __syncthreads();
    if (t < 32) {
        float sv = 0.f, sq = 0.f;
#pragma unroll
        for (int i = 0; i < 16; i++) { float v = sbuf[i][t]; sv += v; sq += v * v; }
        float* sh0 = ws + OFF_STATS + (fb & (NSHADOW_ - 1)) * 128;
        atomicAdd(&sh0[64 + t], sv); atomicAdd(&sh0[96 + t], sq);
    }
    __syncthreads();
    ARRIVE(g_b2s[P], g_b2r[P]);
    SPINROOT(g_b2r[P], 2);
    if (t < 32) {
        float sm = 0.f, sq = 0.f;
#pragma unroll
        for (int k = 0; k < NSHADOW_; k++) {
            sm += aloadf(&ws[OFF_STATS + k * 128 + 64 + t]);
            sq += aloadf(&ws[OFF_STATS + k * 128 + 96 + t]);
        }
        float m = sm * (1.f / NP_);
        float v = sq * (1.f / NP_) - m * m;
        float sc = g2f[t] * rsqrtf(v + EPS_);
        scs[t] = sc; shs[t] = b2f[t] - m * sc;
    }
    __syncthreads();
    // phase C: BN2+ReLU -> z2(LDS) -> conv3 -> A, b (agent-stored)
    if (act) zbuf[pos][ch] = fmaxf(y2 * scs[ch] + shs[ch], 0.f);
    __syncthreads();
    if (t < 48) {
        int pz = t / 3, c = t % 3;
        int p = p0 + pz;
        if (p < NP_) {
            float A = 0.f;
#pragma unroll
            for (int i = 0; i < 32; i++) A += w3L[c * 33 + i] * zbuf[pz][i];
            astoref(&ws[OFF_A  + c * NP_ + p], A);
            astoref(&ws[OFF_BV + c * NP_ + p], myb[pz][c] - A * mxb[pz][c]);
        }
    }
    __syncthreads();                  // drain A/b stores before arrival
    // done barrier; the block completing the root resets the other parity set
    if (t == 0) {
        int old = aadd(&g_b3s[P][(fb & (NSHARD_ - 1)) * LINE_], 1);
        if (old == SHARD_TGT_ - 1) {
            int ro = aadd(&g_b3r[P][0], 1);
            if (ro == NSHARD_ - 1) {
                int Q = P ^ 1;
#pragma unroll
                for (int i = 0; i < NSHARD_; i++) {
                    astorei(&g_b0s[Q][i * LINE_], 0); astorei(&g_b1s[Q][i * LINE_], 0);
                    astorei(&g_b2s[Q][i * LINE_], 0); astorei(&g_b3s[Q][i * LINE_], 0);
                }
                astorei(&g_b0r[Q][0], 0); astorei(&g_b1r[Q][0], 0);
                astorei(&g_b2r[Q][0], 0); astorei(&g_b3r[Q][0], 0);
                __hip_atomic_store(&g_parity, Q, __ATOMIC_RELEASE, __HIP_MEMORY_SCOPE_AGENT);
            }
        }
    }
    SPINROOT(g_b3r[P], 8);

    // ---------------- phase 5: upsample + out = A*g_regs + b (48 rows/block) ----------------
    {
        int row0 = fb * 48 + sub * 16;    // == phase-1 rows of this (fb,sub): g is in gvals
        int bc = row0 >> 10;              // 16-row chunk never crosses bc
        int b5 = bc / 3, c5 = bc % 3;
        const float* Abase = ws + OFF_A  + c5 * NP_ + b5 * NPOSPB_;
        const float* Bbase = ws + OFF_BV + c5 * NP_ + b5 * NPOSPB_;
        int x0_[4], x1_[4]; float wx_[4];
#pragma unroll
        for (int j = 0; j < 4; j++) {
            int x = st * 4 + j;
            float fx = (float)x * (30.f / 1023.f);
            int x0 = (int)fx;
            wx_[j] = fx - (float)x0;
            x0_[j] = x0;
            x1_[j] = min(x0 + 1, 30);
        }
#pragma unroll
        for (int rr = 0; rr < 16; rr++) {    // FULL unroll: gvals[rr] static
            int y = (row0 & 1023) + rr;
            float fy = (float)y * (30.f / 1023.f);
            int y0 = (int)fy;
            float wy = fy - (float)y0;
            int y1i = min(y0 + 1, 30);
            const float* A0 = Abase + y0  * OH_;
            const float* A1 = Abase + y1i * OH_;
            const float* B0 = Bbase + y0  * OH_;
            const float* B1 = Bbase + y1i * OH_;
            size_t rowoff = ((size_t)bc * H_ + (size_t)y) * W_;
            f4 gv = gvals[rr];
            float go[4] = { gv.x, gv.y, gv.z, gv.w };
            float r[4];
#pragma unroll
            for (int j = 0; j < 4; j++) {
                int x0 = x0_[j], x1 = x1_[j];
                float wx = wx_[j];
                float av = (A0[x0] * (1.f - wx) + A0[x1] * wx) * (1.f - wy)
                         + (A1[x0] * (1.f - wx) + A1[x1] * wx) * wy;
                float bb = (B0[x0] * (1.f - wx) + B0[x1] * wx) * (1.f - wy)
                         + (B1[x0] * (1.f - wx) + B1[x1] * wx) * wy;
                r[j] = av * go[j] + bb;
            }
            f4 ov; ov.x = r[0]; ov.y = r[1]; ov.z = r[2]; ov.w = r[3];
            __builtin_nontemporal_store(ov, (f4*)(out + rowoff) + st);   // out never re-read
        }
    }
}

extern "C" void kernel_launch(void* const* d_in, const int* in_sizes, int n_in,
                              void* d_out, int out_size, void* d_ws, size_t ws_size,
                              hipStream_t stream) {
    const float* guide = (const float*)d_in[0];
    const float* src   = (const float*)d_in[1];
    // d_in[2] = box_w (all ones) -- unused; N == 4096 everywhere (VALID padding)
    const float* w1 = (const float*)d_in[3];
    const float* g1 = (const float*)d_in[4];
    const float* b1 = (const float*)d_in[5];
    const float* w2 = (const float*)d_in[6];
    const float* g2 = (const float*)d_in[7];
    const float* b2 = (const float*)d_in[8];
    const float* w3 = (const float*)d_in[9];
    float* ws = (float*)d_ws;
    float* out = (float*)d_out;

    // Plain launch: 256 blocks x 768 threads = 1 block/CU, co-resident by
    // construction (__launch_bounds__(768) caps VGPR so 12 waves fit) -> spin
    // barriers are safe.
    hipLaunchKernelGGL(fused, dim3(NBLK_), dim3(NTHR_), 0, stream,
                       guide, src, w1, g1, b1, w2, g2, b2, w3, ws, out);
}

// Round 10
// 174.988 us; speedup vs baseline: 1.1367x; 1.1367x over previous
//
#include <hip/hip_runtime.h>
#include <stdint.h>

// Problem constants
#define B_      4
#define C_      3
#define H_      1024
#define W_      1024
#define OH_     31          // (1024-64)/32 + 1
#define NHS_    64          // 16-row half-strips per image
#define NP_     3844        // B * OH * OH
#define NPOSPB_ 961         // OH*OH
#define EPS_    1e-5f

#define NBLK2_   128        // kmid grid: 128 blocks x 1024 threads, 32 positions/block
#define NSHARD_  8
#define SHARD_TGT_ 16       // 128 / 8
#define LINE_    32         // ints per 128B line
#define NSHADOW_ 8          // BN-stats shadow accumulators

// ---------------- ws layout (float offsets) ----------------
#define TILE_PLANE 24576    // 12 bc * 64 hs * 32 tx
#define OFF_TILE  0         // 4 planes * 24576 = 98304
#define OFF_STATS 98304     // 8 shadows * 128 = 1024
#define OFF_A     99328     // 3 * 3844
#define OFF_BV    110860    // 3 * 3844  (end 122392 floats ~= 490 KB)

typedef float f4 __attribute__((ext_vector_type(4)));

// ---------------- parity-versioned barrier state (device globals, zero-init) ----------------
// Two barriers (BN1, BN2) x two parity sets. The block that completes BN2's
// root resets the OTHER parity set and release-stores g_parity -> next launch
// (and every rocprof replay / graph replay) sees a clean set. Proven r6-r8.
__device__ int g_b1s[2][NSHARD_ * LINE_]; __device__ int g_b1r[2][LINE_];
__device__ int g_b2s[2][NSHARD_ * LINE_]; __device__ int g_b2r[2][LINE_];
__device__ int g_parity;

// Proven round-6/7 recipe: poll with RELAXED agent loads (read-through, no
// cache maintenance); ONE acquire load after the predicate passes does the
// single L1/L2 invalidate + ordering. Acquire-per-poll = L2-invalidate storm.
static __device__ __forceinline__ int  rload(int* p) { return __hip_atomic_load(p, __ATOMIC_RELAXED, __HIP_MEMORY_SCOPE_AGENT); }
static __device__ __forceinline__ int  aacq(int* p)  { return __hip_atomic_load(p, __ATOMIC_ACQUIRE, __HIP_MEMORY_SCOPE_AGENT); }
static __device__ __forceinline__ int  aadd(int* p, int v) { return __hip_atomic_fetch_add(p, v, __ATOMIC_ACQ_REL, __HIP_MEMORY_SCOPE_AGENT); }
static __device__ __forceinline__ void astorei(int* p, int v) { __hip_atomic_store(p, v, __ATOMIC_RELAXED, __HIP_MEMORY_SCOPE_AGENT); }
static __device__ __forceinline__ float aloadf(float* p) { return __hip_atomic_load(p, __ATOMIC_RELAXED, __HIP_MEMORY_SCOPE_AGENT); }

// ---------------- K1: 16-row half-strip partial sums (proven round-0..4; ~HBM floor) ----------------
// grid = 768 blocks x 256 threads. Plain stores; kernel-boundary flush gives
// kmid coherent visibility (how rounds 0-4 always worked).
__global__ __launch_bounds__(256) void k1_tilesums(
        const float* __restrict__ g,
        const float* __restrict__ s,
        float* __restrict__ ws) {
    int blk = blockIdx.x;
    int bc = blk >> 6;        // 0..11
    int hs = blk & 63;        // half-strip (16 rows)
    int t  = threadIdx.x;     // covers columns [4t, 4t+4)
    const f4* gp = (const f4*)(g + ((size_t)bc * H_ + (size_t)hs * 16) * W_);
    const f4* sp = (const f4*)(s + ((size_t)bc * H_ + (size_t)hs * 16) * W_);
    float sg = 0.f, ss = 0.f, sgs = 0.f, sgg = 0.f;
#pragma unroll 4
    for (int r = 0; r < 16; r++) {
        f4 gv = gp[r * (W_ / 4) + t];
        f4 sv = __builtin_nontemporal_load(sp + r * (W_ / 4) + t);  // src read exactly once
        sg  += (gv.x + gv.y) + (gv.z + gv.w);
        ss  += (sv.x + sv.y) + (sv.z + sv.w);
        sgs += gv.x * sv.x + gv.y * sv.y + gv.z * sv.z + gv.w * sv.w;
        sgg += gv.x * gv.x + gv.y * gv.y + gv.z * gv.z + gv.w * gv.w;
    }
#pragma unroll
    for (int off = 4; off; off >>= 1) {
        sg  += __shfl_down(sg,  off, 8);
        ss  += __shfl_down(ss,  off, 8);
        sgs += __shfl_down(sgs, off, 8);
        sgg += __shfl_down(sgg, off, 8);
    }
    if ((t & 7) == 0) {
        int tx = t >> 3;
        int base = (bc * NHS_ + hs) * 32 + tx;
        ws[OFF_TILE + 0 * TILE_PLANE + base] = sg;
        ws[OFF_TILE + 1 * TILE_PLANE + base] = ss;
        ws[OFF_TILE + 2 * TILE_PLANE + base] = sgs;
        ws[OFF_TILE + 3 * TILE_PLANE + base] = sgg;
    }
    // zero the 8 shadow stats accumulators (ws is poisoned each launch)
    if (blk == 0) for (int i = t; i < NSHADOW_ * 128; i += 256) ws[OFF_STATS + i] = 0.f;
}

// ============================================================================
// KMID v2: 128 blocks x 1024 threads, thread = (pos 0..31, ch 0..31).
// vs round-4 kmid (16 blocks, 41.6 us): scattered S-loads deduplicated
// (384 threads x 8 loads, was 96/thread with 4x redundancy), 8x more CUs,
// all 1024 threads active in conv1/conv2, only 2 cross-block barriers.
// Weights in padded LDS (w2 stride 33 -> (ch+i)&31 conflict-free).
// BN stats: block partial (32 lanes) -> shadow accumulator (16 RMW/addr) ->
// sharded barrier -> sum 8 shadows. A/b plain stores; kernel-boundary flush
// makes them coherent for k5.
// Co-residency (spin-safety): __launch_bounds__(1024) caps VGPR<=64 ->
// 16 waves/block fit any CU; 128 blocks <= 256 CUs -> all dispatched
// before any can block on the barrier.
// ============================================================================
__global__ __launch_bounds__(1024) void kmid(
        const float* __restrict__ w1f,
        const float* __restrict__ g1f,
        const float* __restrict__ b1f,
        const float* __restrict__ w2f,
        const float* __restrict__ g2f,
        const float* __restrict__ b2f,
        const float* __restrict__ w3f,
        float* __restrict__ ws) {
    __shared__ float w1L[192];
    __shared__ float w2L[32 * 33];
    __shared__ float w3L[3 * 33];
    __shared__ float Sarr[32][12];     // [pos][c*4+plane]
    __shared__ float hbuf[32][8];      // h[0..5]
    __shared__ float mxb[32][4], myb[32][4];
    __shared__ float sbuf[32][33];     // stats staging (y1, then y2), stride-33
    __shared__ float zbuf[32][33];     // z, then z2
    __shared__ float scs[32], shs[32];
    __shared__ int sP;
    int t  = threadIdx.x;
    int fb = blockIdx.x;
    if (t == 0) sP = rload(&g_parity);

    // weights -> LDS (one element per thread for w2)
    if (t < 192) w1L[t] = w1f[t];
    w2L[(t >> 5) * 33 + (t & 31)] = w2f[t];          // t = 0..1023 exactly
    if (t >= 256 && t < 352) { int i = t - 256; w3L[(i / 32) * 33 + (i & 31)] = w3f[i]; }

    int p0 = fb * 32;
    // ---- S sums: 384 threads x one (pos,c,plane), 8 scattered loads each ----
    if (t < 384) {
        int ipos = t / 12, idx = t % 12;
        int c = idx >> 2, plane = idx & 3;
        int p = p0 + ipos; if (p >= NP_) p = 0;      // clamp (excluded downstream)
        int b = p / NPOSPB_, r = p % NPOSPB_;
        int oy = r / OH_, ox = r % OH_;
        const float* tp = ws + OFF_TILE + plane * TILE_PLANE + ((b * 3 + c) * NHS_ + oy * 2) * 32 + ox;
        Sarr[ipos][idx] = ((tp[0]  + tp[1])  + (tp[32] + tp[33]))
                        + ((tp[64] + tp[65]) + (tp[96] + tp[97]));
    }
    __syncthreads();
    // ---- h, mx, my ----
    if (t < 96) {
        int pos = t / 3, c = t % 3;
        const float inv = 1.f / 4096.f;
        float mx = Sarr[pos][c * 4 + 0] * inv, my = Sarr[pos][c * 4 + 1] * inv;
        hbuf[pos][c]     = Sarr[pos][c * 4 + 2] * inv - mx * my;
        hbuf[pos][3 + c] = Sarr[pos][c * 4 + 3] * inv - mx * mx;
        mxb[pos][c] = mx; myb[pos][c] = my;
    }
    __syncthreads();
    // ---- conv1: all 1024 threads, y1 stays in a register ----
    int pos = t >> 5, ch = t & 31;
    bool valid = (p0 + pos) < NP_;
    float y1 = 0.f;
#pragma unroll
    for (int i = 0; i < 6; i++) y1 += w1L[ch * 6 + i] * hbuf[pos][i];   // broadcast
    sbuf[pos][ch] = valid ? y1 : 0.f;
    __syncthreads();
    if (t < 32) {                      // block partial -> shadow accumulator
        float sv = 0.f, sq = 0.f;
#pragma unroll
        for (int i = 0; i < 32; i++) { float v = sbuf[i][t]; sv += v; sq += v * v; }
        float* sh0 = ws + OFF_STATS + (fb & (NSHADOW_ - 1)) * 128;
        atomicAdd(&sh0[t], sv); atomicAdd(&sh0[32 + t], sq);
    }
    __syncthreads();                   // drains the adders' vmcnt
    int P = sP;
    // ---- BN1 barrier (sharded arrive, relaxed poll, single acquire) ----
    if (t == 0) {
        int o = aadd(&g_b1s[P][(fb & (NSHARD_ - 1)) * LINE_], 1);
        if (o == SHARD_TGT_ - 1) aadd(&g_b1r[P][0], 1);
        while (rload(&g_b1r[P][0]) < NSHARD_) __builtin_amdgcn_s_sleep(4);
        (void)aacq(&g_b1r[P][0]);
    }
    __syncthreads();
    if (t < 32) {
        float sm = 0.f, sq = 0.f;
#pragma unroll
        for (int k = 0; k < NSHADOW_; k++) {
            sm += aloadf(&ws[OFF_STATS + k * 128 + t]);
            sq += aloadf(&ws[OFF_STATS + k * 128 + 32 + t]);
        }
        float m = sm * (1.f / NP_);
        float v = sq * (1.f / NP_) - m * m;
        float sc = g1f[t] * rsqrtf(v + EPS_);
        scs[t] = sc; shs[t] = b1f[t] - m * sc;
    }
    __syncthreads();
    // ---- BN1+ReLU -> z(LDS) -> conv2 ----
    zbuf[pos][ch] = fmaxf(y1 * scs[ch] + shs[ch], 0.f);
    __syncthreads();
    float y2 = 0.f;
#pragma unroll
    for (int i = 0; i < 32; i++) y2 += w2L[ch * 33 + i] * zbuf[pos][i];  // conflict-free
    sbuf[pos][ch] = valid ? y2 : 0.f;
    __syncthreads();
    if (t < 32) {
        float sv = 0.f, sq = 0.f;
#pragma unroll
        for (int i = 0; i < 32; i++) { float v = sbuf[i][t]; sv += v; sq += v * v; }
        float* sh0 = ws + OFF_STATS + (fb & (NSHADOW_ - 1)) * 128;
        atomicAdd(&sh0[64 + t], sv); atomicAdd(&sh0[96 + t], sq);
    }
    __syncthreads();
    // ---- BN2 barrier; completer resets the OTHER parity set + flips parity ----
    if (t == 0) {
        int o = aadd(&g_b2s[P][(fb & (NSHARD_ - 1)) * LINE_], 1);
        if (o == SHARD_TGT_ - 1) {
            int ro = aadd(&g_b2r[P][0], 1);
            if (ro == NSHARD_ - 1) {
                int Q = P ^ 1;
#pragma unroll
                for (int i = 0; i < NSHARD_; i++) {
                    astorei(&g_b1s[Q][i * LINE_], 0);
                    astorei(&g_b2s[Q][i * LINE_], 0);
                }
                astorei(&g_b1r[Q][0], 0);
                astorei(&g_b2r[Q][0], 0);
                __hip_atomic_store(&g_parity, Q, __ATOMIC_RELEASE, __HIP_MEMORY_SCOPE_AGENT);
            }
        }
        while (rload(&g_b2r[P][0]) < NSHARD_) __builtin_amdgcn_s_sleep(4);
        (void)aacq(&g_b2r[P][0]);
    }
    __syncthreads();
    if (t < 32) {
        float sm = 0.f, sq = 0.f;
#pragma unroll
        for (int k = 0; k < NSHADOW_; k++) {
            sm += aloadf(&ws[OFF_STATS + k * 128 + 64 + t]);
            sq += aloadf(&ws[OFF_STATS + k * 128 + 96 + t]);
        }
        float m = sm * (1.f / NP_);
        float v = sq * (1.f / NP_) - m * m;
        float sc = g2f[t] * rsqrtf(v + EPS_);
        scs[t] = sc; shs[t] = b2f[t] - m * sc;
    }
    __syncthreads();
    // ---- BN2+ReLU -> z2(LDS) -> conv3 -> A, b (plain stores; boundary flush) ----
    zbuf[pos][ch] = fmaxf(y2 * scs[ch] + shs[ch], 0.f);
    __syncthreads();
    if (t < 96) {
        int pz = t / 3, c = t % 3;
        int p = p0 + pz;
        if (p < NP_) {
            float A = 0.f;
#pragma unroll
            for (int i = 0; i < 32; i++) A += w3L[c * 33 + i] * zbuf[pz][i];
            ws[OFF_A  + c * NP_ + p] = A;
            ws[OFF_BV + c * NP_ + p] = myb[pz][c] - A * mxb[pz][c];
        }
    }
}

// ---------------- K5: bilinear upsample (align_corners) + out = A*g + b (proven round-0..4) ----------------
__global__ __launch_bounds__(256) void k5_final(
        const float* __restrict__ g,
        const float* __restrict__ ws,
        float* __restrict__ out) {
    int blk = blockIdx.x;
    int y  = blk & 1023;
    int bc = blk >> 10;
    int b = bc / 3, c = bc % 3;
    float fy = (float)y * (30.f / 1023.f);
    int y0 = (int)fy;
    float wy = fy - (float)y0;
    int y1i = min(y0 + 1, 30);
    const float* A0 = ws + OFF_A  + c * NP_ + b * NPOSPB_ + y0  * OH_;
    const float* A1 = ws + OFF_A  + c * NP_ + b * NPOSPB_ + y1i * OH_;
    const float* B0 = ws + OFF_BV + c * NP_ + b * NPOSPB_ + y0  * OH_;
    const float* B1 = ws + OFF_BV + c * NP_ + b * NPOSPB_ + y1i * OH_;
    int t = threadIdx.x;
    size_t rowoff = ((size_t)bc * H_ + (size_t)y) * W_;
    const f4* gp = (const f4*)(g + rowoff);
    f4* op = (f4*)(out + rowoff);
    f4 gv = gp[t];
    float go[4] = { gv.x, gv.y, gv.z, gv.w };
    float r[4];
#pragma unroll
    for (int j = 0; j < 4; j++) {
        int x = t * 4 + j;
        float fx = (float)x * (30.f / 1023.f);
        int x0 = (int)fx;
        float wx = fx - (float)x0;
        int x1 = min(x0 + 1, 30);
        float a  = (A0[x0] * (1.f - wx) + A0[x1] * wx) * (1.f - wy)
                 + (A1[x0] * (1.f - wx) + A1[x1] * wx) * wy;
        float bb = (B0[x0] * (1.f - wx) + B0[x1] * wx) * (1.f - wy)
                 + (B1[x0] * (1.f - wx) + B1[x1] * wx) * wy;
        r[j] = a * go[j] + bb;
    }
    f4 ov;
    ov.x = r[0]; ov.y = r[1]; ov.z = r[2]; ov.w = r[3];
    __builtin_nontemporal_store(ov, op + t);   // out never re-read
}

extern "C" void kernel_launch(void* const* d_in, const int* in_sizes, int n_in,
                              void* d_out, int out_size, void* d_ws, size_t ws_size,
                              hipStream_t stream) {
    const float* guide = (const float*)d_in[0];
    const float* src   = (const float*)d_in[1];
    // d_in[2] = box_w (all ones) -- unused; N == 4096 everywhere (VALID padding)
    const float* w1 = (const float*)d_in[3];
    const float* g1 = (const float*)d_in[4];
    const float* b1 = (const float*)d_in[5];
    const float* w2 = (const float*)d_in[6];
    const float* g2 = (const float*)d_in[7];
    const float* b2 = (const float*)d_in[8];
    const float* w3 = (const float*)d_in[9];
    float* ws = (float*)d_ws;
    float* out = (float*)d_out;

    hipLaunchKernelGGL(k1_tilesums, dim3(B_ * C_ * NHS_), dim3(256),  0, stream, guide, src, ws);
    // 128 blocks x 1024 threads: <= 256 CUs -> co-resident by construction; spin barriers safe
    hipLaunchKernelGGL(kmid,        dim3(NBLK2_),         dim3(1024), 0, stream,
                       w1, g1, b1, w2, g2, b2, w3, ws);
    hipLaunchKernelGGL(k5_final,    dim3(B_ * C_ * H_),   dim3(256),  0, stream, guide, ws, out);
}